// Round 19
// baseline (561.408 us; speedup 1.0000x reference)
//
#include <hip/hip_runtime.h>
#include <cmath>

typedef unsigned short u16;
typedef unsigned int u32;
typedef short bf16x8 __attribute__((ext_vector_type(8)));
typedef float f32x4 __attribute__((ext_vector_type(4)));

#define DEVI __device__ __forceinline__

constexpr int NSEQ = 4096, DIMM = 512;
constexpr int KVLD = 1024;   // kv combined row stride
constexpr int MP = 288;      // padded feature dim (266 -> 18*16)
constexpr int MPP = 296;     // qpL LDS row stride (bank-conflict-free)
constexpr int MREAL = 266;
constexpr int DHP = 96;      // 64 v-cols + ones col + zero pad
constexpr float LNEPS = 1e-5f;
constexpr float KEPS = 1e-4f;
constexpr float DN = 0.3535533905932738f;      // 64^-0.25
constexpr float HALF_DN2 = 0.0625f;            // 0.5 * 64^-0.5

DEVI u16 f2bf(float f) {
  u32 u = __float_as_uint(f);
  u32 r = (u + 0x7FFFu + ((u >> 16) & 1u)) >> 16;
  return (u16)r;
}
DEVI float bf2f(u16 h) { return __uint_as_float(((u32)h) << 16); }

DEVI f32x4 mfma16(bf16x8 a, bf16x8 b, f32x4 c) {
  return __builtin_amdgcn_mfma_f32_16x16x32_bf16(a, b, c, 0, 0, 0);
}

DEVI void gload_lds16(const void* g, void* l) {
  __builtin_amdgcn_global_load_lds(
      (const __attribute__((address_space(1))) u32*)g,
      (__attribute__((address_space(3))) u32*)l, 16, 0, 0);
}

// tanh-form GELU: z * e/(e+1), e = exp(1.5957691*(z + 0.044715 z^3))
DEVI float gelu_fast(float z) {
  float a = fminf(1.5957691216057308f * (z + 0.044715f * z * z * z), 60.f);
  float e = __expf(a);
  return z * e * __builtin_amdgcn_rcpf(e + 1.f);
}

// ---------------- diagnostics ----------------
__global__ void ws_sentinel(float* out) { out[0] = 12345.0f; }

// ---------------- weight prep ----------------
__launch_bounds__(256)
__global__ void transpose_cvt(const float* __restrict__ in, u16* __restrict__ out,
                              int K, int Nn) {
  __shared__ float tl[32][33];
  int ntn = Nn >> 5;
  int bid = blockIdx.x;
  int kt = bid / ntn, ntt = bid - kt * ntn;
  int k0 = kt << 5, nn0 = ntt << 5;
  int t = threadIdx.x;
  int r = t >> 5, c = t & 31;
#pragma unroll
  for (int i = 0; i < 4; ++i)
    tl[r + i * 8][c] = in[(size_t)(k0 + r + i * 8) * Nn + nn0 + c];
  __syncthreads();
#pragma unroll
  for (int i = 0; i < 4; ++i)
    out[(size_t)(nn0 + r + i * 8) * K + k0 + c] = f2bf(tl[c][r + i * 8]);
}

// projf: B-fragment layout [f][half][lane][8] for direct register loads
__global__ void proj_prep(const float* __restrict__ proj, u16* __restrict__ projf) {
  int idx = blockIdx.x * 256 + threadIdx.x;
  if (idx >= MP * 64) return;
  int e = idx & 7, lane = (idx >> 3) & 63, fh = idx >> 9;
  int f = fh >> 1, half = fh & 1;
  int m = f * 16 + (lane & 15);
  int d = half * 32 + (lane >> 4) * 8 + e;
  float v = (m < MREAL) ? proj[m * 64 + d] * DN : 0.f;
  projf[idx] = f2bf(v);
}

// w1f: A-operand fragment layout [hcolf(128)][k16(16)][lane][8]
//   value = W1[k][hcol], hcol = hcolf*16 + (lane&15), k = k16*32 + (lane>>4)*8 + e
__global__ void w1_prep(const float* __restrict__ w1, u16* __restrict__ w1f) {
  int idx = blockIdx.x * 256 + threadIdx.x;   // < 128*16*512 = 1048576
  int e = idx & 7, lane = (idx >> 3) & 63;
  int k16 = (idx >> 9) & 15, hcf = idx >> 13;
  int hcol = hcf * 16 + (lane & 15);
  int k = k16 * 32 + (lane >> 4) * 8 + e;
  w1f[idx] = f2bf(w1[(size_t)k * 2048 + hcol]);
}

// w2f: B-operand fragment layout [ocolf(32)][hk16(64)][lane][8]
//   value = W2[hk][ocol], ocol = ocolf*16 + (lane&15), hk = hk16*32 + (lane>>4)*8 + e
__global__ void w2_prep(const float* __restrict__ w2, u16* __restrict__ w2f) {
  int idx = blockIdx.x * 256 + threadIdx.x;   // < 32*64*512 = 1048576
  int e = idx & 7, lane = (idx >> 3) & 63;
  int hk16 = (idx >> 9) & 63, ocf = idx >> 15;
  int ocol = ocf * 16 + (lane & 15);
  int hk = hk16 * 32 + (lane >> 4) * 8 + e;
  w2f[idx] = f2bf(w2[(size_t)hk * 512 + ocol]);
}

// ---------------- layernorm (one wave per row) ----------------
__launch_bounds__(256)
__global__ void ln_fwd(const float* __restrict__ x, const float* __restrict__ g,
                       const float* __restrict__ bt, u16* __restrict__ out) {
  int w = threadIdx.x >> 6, lane = threadIdx.x & 63;
  int row = blockIdx.x * 4 + w;
  const float* xr = x + (size_t)row * DIMM;
  int c0 = lane * 4;
  float4 v0 = *(const float4*)(xr + c0);
  float4 v1 = *(const float4*)(xr + 256 + c0);
  float s = v0.x + v0.y + v0.z + v0.w + v1.x + v1.y + v1.z + v1.w;
  float sq = v0.x * v0.x + v0.y * v0.y + v0.z * v0.z + v0.w * v0.w +
             v1.x * v1.x + v1.y * v1.y + v1.z * v1.z + v1.w * v1.w;
#pragma unroll
  for (int mk = 1; mk < 64; mk <<= 1) {
    s += __shfl_xor(s, mk, 64);
    sq += __shfl_xor(sq, mk, 64);
  }
  float mu = s * (1.f / 512.f);
  float var = sq * (1.f / 512.f) - mu * mu;
  float rstd = rsqrtf(var + LNEPS);
  float4 g0 = *(const float4*)(g + c0);
  float4 g1 = *(const float4*)(g + 256 + c0);
  float4 b0 = *(const float4*)(bt + c0);
  float4 b1 = *(const float4*)(bt + 256 + c0);
  u16* orow = out + (size_t)row * DIMM;
  uint2 p0, p1;
  {
    u16 h0 = f2bf((v0.x - mu) * rstd * g0.x + b0.x);
    u16 h1 = f2bf((v0.y - mu) * rstd * g0.y + b0.y);
    u16 h2 = f2bf((v0.z - mu) * rstd * g0.z + b0.z);
    u16 h3 = f2bf((v0.w - mu) * rstd * g0.w + b0.w);
    p0.x = ((u32)h1 << 16) | h0; p0.y = ((u32)h3 << 16) | h2;
  }
  {
    u16 h0 = f2bf((v1.x - mu) * rstd * g1.x + b1.x);
    u16 h1 = f2bf((v1.y - mu) * rstd * g1.y + b1.y);
    u16 h2 = f2bf((v1.z - mu) * rstd * g1.z + b1.z);
    u16 h3 = f2bf((v1.w - mu) * rstd * g1.w + b1.w);
    p1.x = ((u32)h1 << 16) | h0; p1.y = ((u32)h3 << 16) | h2;
  }
  *(uint2*)(orow + c0) = p0;
  *(uint2*)(orow + 256 + c0) = p1;
}

// -- 256x256 bf16 GEMM, BK=64, 512 threads (8 waves, 2Mx4N), dbuf LDS 128KB.
//    R7 v3 schedule (best measured): 24 fragments up front; half MFMAs;
//    lgkmcnt(0)+sched_barrier+barrier; stage; remaining MFMAs overlap flight.
// EPI: 0 = bf16 out; 1 = fp32 out + bias + residual
#define WAITVM(N) asm volatile("s_waitcnt vmcnt(" #N ")" ::: "memory")

template <int EPI>
__launch_bounds__(512)
__global__ void gemm256(const u16* __restrict__ A, int lda,
                        const u16* __restrict__ Bt, int ldb, int K,
                        void* __restrict__ OutP, int Nout, int ldo,
                        const float* __restrict__ bias,
                        const float* __restrict__ Res) {
  __shared__ __align__(16) u16 Al[2][256 * 64];
  __shared__ __align__(16) u16 Bl[2][256 * 64];
  int ntiles = Nout >> 8;
  int nwg = gridDim.x;
  int bid = blockIdx.x;
  int cpx = nwg >> 3;                       // grids are multiples of 8
  int wg = (bid & 7) * cpx + (bid >> 3);    // XCD swizzle (bijective: nwg%8==0)
  int mt = wg / ntiles, nt = wg - mt * ntiles;
  int t = threadIdx.x, lane = t & 63, w = t >> 6;
  int wm = w >> 2, wn = w & 3;              // wave grid 2M x 4N
  int fr = lane & 15, fq = lane >> 4;
  int rowA0 = mt * 256, colB0 = nt * 256;
  int swz = (fr & 7) << 4;                  // read-side XOR (row&7 == fr&7)

  f32x4 acc[8][4];
#pragma unroll
  for (int i = 0; i < 8; ++i)
#pragma unroll
    for (int j = 0; j < 4; ++j) acc[i][j] = f32x4{0.f, 0.f, 0.f, 0.f};

  int srow = t >> 3;                                   // 0..63
  int so = ((t * 16) & 127) ^ ((srow & 7) << 4);       // swizzled in-row byte

#define STAGE_G(bufi, k0)                                                       \
  do {                                                                          \
    _Pragma("unroll") for (int it = 0; it < 4; ++it) {                          \
      gload_lds16(                                                              \
          (const char*)(A + ((size_t)(rowA0 + srow + it * 64) * lda + (k0))) + so, \
          (char*)Al[bufi] + t * 16 + it * 8192);                                \
      gload_lds16(                                                              \
          (const char*)(Bt + ((size_t)(colB0 + srow + it * 64) * ldb + (k0))) + so, \
          (char*)Bl[bufi] + t * 16 + it * 8192);                                \
    }                                                                           \
  } while (0)

  int NT = K >> 6;
  STAGE_G(0, 0);
  STAGE_G(1, 64);
  int bi = 0;
  for (int tt = 0; tt < NT; ++tt) {
    if (tt + 1 < NT) { WAITVM(8); } else { WAITVM(0); }
    __builtin_amdgcn_s_barrier();   // all waves: stage tt visible in LDS

    bf16x8 av[8][2], bv[4][2];
#pragma unroll
    for (int i = 0; i < 8; ++i)
#pragma unroll
      for (int ks = 0; ks < 2; ++ks) {
        int row = wm * 128 + i * 16 + fr;
        av[i][ks] = *(const bf16x8*)((const char*)Al[bi] + row * 128 +
                                     (((ks << 6) | (fq << 4)) ^ swz));
      }
#pragma unroll
    for (int j = 0; j < 4; ++j)
#pragma unroll
      for (int ks = 0; ks < 2; ++ks) {
        int row = wn * 64 + (j)*16 + fr;
        bv[j][ks] = *(const bf16x8*)((const char*)Bl[bi] + row * 128 +
                                     (((ks << 6) | (fq << 4)) ^ swz));
      }

    __builtin_amdgcn_s_setprio(1);
#pragma unroll
    for (int i = 0; i < 4; ++i)
#pragma unroll
      for (int j = 0; j < 4; ++j)
#pragma unroll
        for (int ks = 0; ks < 2; ++ks)
          acc[i][j] = mfma16(av[i][ks], bv[j][ks], acc[i][j]);
    __builtin_amdgcn_s_setprio(0);

    asm volatile("s_waitcnt lgkmcnt(0)" ::: "memory");
    __builtin_amdgcn_sched_barrier(0);
    __builtin_amdgcn_s_barrier();
    if (tt + 2 < NT) STAGE_G(bi, (tt + 2) * 64);

    __builtin_amdgcn_s_setprio(1);
#pragma unroll
    for (int i = 4; i < 8; ++i)
#pragma unroll
      for (int j = 0; j < 4; ++j)
#pragma unroll
        for (int ks = 0; ks < 2; ++ks)
          acc[i][j] = mfma16(av[i][ks], bv[j][ks], acc[i][j]);
    __builtin_amdgcn_s_setprio(0);
    bi ^= 1;
  }
#undef STAGE_G

#pragma unroll
  for (int i = 0; i < 8; ++i)
#pragma unroll
    for (int j = 0; j < 4; ++j) {
      int row = rowA0 + wm * 128 + i * 16 + fq * 4;
      int col = colB0 + wn * 64 + j * 16 + fr;
#pragma unroll
      for (int r = 0; r < 4; ++r) {
        float v = acc[i][j][r];
        size_t idx = (size_t)(row + r) * ldo + col;
        if constexpr (EPI == 0) {
          ((u16*)OutP)[idx] = f2bf(v);
        } else {
          ((float*)OutP)[idx] = v + bias[col] + Res[(size_t)(row + r) * 512 + col];
        }
      }
    }
}

// -- fused FFN v7 = v6 (LN2-fused staging, R18-best) + w2 register prefetch
//    with the VGPR cap LIFTED via __launch_bounds__(512, 1): R16's failure
//    was the allocator's 128-VGPR default under (512); at our real occupancy
//    (8 waves = 2/SIMD) the HW budget is 256/wave. Dual prefetch plan ~230
//    VGPR fits. w2c hoisted to chunk top -> flies across first gemm + pack
//    + barrier; w1c reload (proven +40us) unchanged.
__launch_bounds__(512, 1)
__global__ void ffn_fused(float* __restrict__ dout, const float* __restrict__ ln2g,
                          const float* __restrict__ ln2b,
                          const u16* __restrict__ w1f, const u16* __restrict__ w2f,
                          const float* __restrict__ b1, const float* __restrict__ b2) {
  __shared__ __align__(16) u16 As[64 * 512];    // 64 KB, 8-chunk swizzle
  __shared__ __align__(16) u16 hS[64 * 128];    // 16 KB, 16-chunk swizzle
  int nwg = gridDim.x;                          // 512
  int bid = blockIdx.x;
  int cpx = nwg >> 3;
  int wg = (bid & 7) * cpx + (bid >> 3);        // XCD swizzle
  int row0 = wg * 64;
  int t = threadIdx.x, lane = t & 63, w = t >> 6;
  int fr = lane & 15, fq = lane >> 4;

  // prologue: issue chunk 0's w1 fragment loads FIRST (latency hides under LN)
  bf16x8 w1c[16];
  {
    const u16* w1p = w1f + ((size_t)(0 * 8 + w) * 16) * 512 + lane * 8;
#pragma unroll
    for (int kk = 0; kk < 16; ++kk) w1c[kk] = *(const bf16x8*)(w1p + kk * 512);
  }

  // fused LN2 staging: wave w normalizes rows w*8 .. w*8+7 into As (swizzled)
  {
    int c0 = lane * 4;
    float4 g0 = *(const float4*)(ln2g + c0);
    float4 g1 = *(const float4*)(ln2g + 256 + c0);
    float4 b0 = *(const float4*)(ln2b + c0);
    float4 b1v = *(const float4*)(ln2b + 256 + c0);
    int lc0 = lane >> 1, half = (lane & 1) * 8;
#pragma unroll
    for (int rr8 = 0; rr8 < 8; ++rr8) {
      int rr = w * 8 + rr8;
      const float* xr = dout + (size_t)(row0 + rr) * 512;
      float4 v0 = *(const float4*)(xr + c0);
      float4 v1 = *(const float4*)(xr + 256 + c0);
      float s = v0.x + v0.y + v0.z + v0.w + v1.x + v1.y + v1.z + v1.w;
      float sq = v0.x * v0.x + v0.y * v0.y + v0.z * v0.z + v0.w * v0.w +
                 v1.x * v1.x + v1.y * v1.y + v1.z * v1.z + v1.w * v1.w;
#pragma unroll
      for (int mk = 1; mk < 64; mk <<= 1) {
        s += __shfl_xor(s, mk, 64);
        sq += __shfl_xor(sq, mk, 64);
      }
      float mu = s * (1.f / 512.f);
      float var = sq * (1.f / 512.f) - mu * mu;
      float rstd = rsqrtf(var + LNEPS);
      uint2 p0, p1;
      {
        u16 h0 = f2bf((v0.x - mu) * rstd * g0.x + b0.x);
        u16 h1 = f2bf((v0.y - mu) * rstd * g0.y + b0.y);
        u16 h2 = f2bf((v0.z - mu) * rstd * g0.z + b0.z);
        u16 h3 = f2bf((v0.w - mu) * rstd * g0.w + b0.w);
        p0.x = ((u32)h1 << 16) | h0; p0.y = ((u32)h3 << 16) | h2;
      }
      {
        u16 h0 = f2bf((v1.x - mu) * rstd * g1.x + b1v.x);
        u16 h1 = f2bf((v1.y - mu) * rstd * g1.y + b1v.y);
        u16 h2 = f2bf((v1.z - mu) * rstd * g1.z + b1v.z);
        u16 h3 = f2bf((v1.w - mu) * rstd * g1.w + b1v.w);
        p1.x = ((u32)h1 << 16) | h0; p1.y = ((u32)h3 << 16) | h2;
      }
      // logical chunk lc holds cols [lc*8, lc*8+8); physical = lc ^ (rr&7)
      *(uint2*)((char*)As + rr * 1024 + ((lc0 ^ (rr & 7)) << 4) + half) = p0;
      *(uint2*)((char*)As + rr * 1024 + (((32 + lc0) ^ (rr & 7)) << 4) + half) = p1;
    }
  }

  f32x4 acc2[4][4];
#pragma unroll
  for (int i = 0; i < 4; ++i)
#pragma unroll
    for (int j = 0; j < 4; ++j) acc2[i][j] = f32x4{0.f, 0.f, 0.f, 0.f};

  __syncthreads();   // As (ds_writes) visible block-wide

  for (int ch = 0; ch < 16; ++ch) {
    // w2 prefetch: issue this chunk's 16 w2 fragments now; they fly across
    // the first gemm + pack + barrier before their first use below.
    bf16x8 w2c[4][4];
#pragma unroll
    for (int k16 = 0; k16 < 4; ++k16)
#pragma unroll
      for (int j = 0; j < 4; ++j)
        w2c[k16][j] = *(const bf16x8*)(w2f +
                       ((size_t)((w * 4 + j) * 64 + ch * 4 + k16)) * 512 + lane * 8);

    // ---- first gemm: wave w computes hcols [ch*128+w*16, +16) x rows 0..63
    f32x4 acch[4];
#pragma unroll
    for (int i = 0; i < 4; ++i) acch[i] = f32x4{0.f, 0.f, 0.f, 0.f};
#pragma unroll
    for (int kk = 0; kk < 16; ++kk) {
      bf16x8 av = w1c[kk];
#pragma unroll
      for (int i = 0; i < 4; ++i) {
        int r = i * 16 + fr;
        bf16x8 bv = *(const bf16x8*)((const char*)As + r * 1024 +
                                     (((kk * 4 + fq) ^ (r & 7)) << 4));
        acch[i] = mfma16(av, bv, acch[i]);
      }
    }
    // w1c dead -> prefetch next chunk's w1 into the same registers now;
    // loads overlap the pack + barrier + entire second gemm.
    if (ch + 1 < 16) {
      const u16* w1p = w1f + ((size_t)((ch + 1) * 8 + w) * 16) * 512 + lane * 8;
#pragma unroll
      for (int kk = 0; kk < 16; ++kk) w1c[kk] = *(const bf16x8*)(w1p + kk * 512);
    }
    // gelu(. + b1) + cvt_pk pack + swizzled b64 write into hS
    float bb0 = b1[ch * 128 + w * 16 + fq * 4 + 0];
    float bb1 = b1[ch * 128 + w * 16 + fq * 4 + 1];
    float bb2 = b1[ch * 128 + w * 16 + fq * 4 + 2];
    float bb3 = b1[ch * 128 + w * 16 + fq * 4 + 3];
    int lcw = w * 2 + (fq >> 1);                // logical 16B chunk in 256B row
#pragma unroll
    for (int i = 0; i < 4; ++i) {
      int arow = i * 16 + fr;
      float g0 = gelu_fast(acch[i][0] + bb0);
      float g1 = gelu_fast(acch[i][1] + bb1);
      float g2 = gelu_fast(acch[i][2] + bb2);
      float g3 = gelu_fast(acch[i][3] + bb3);
      u32 lo, hi;
      asm("v_cvt_pk_bf16_f32 %0, %1, %2" : "=v"(lo) : "v"(g0), "v"(g1));
      asm("v_cvt_pk_bf16_f32 %0, %1, %2" : "=v"(hi) : "v"(g2), "v"(g3));
      uint2 pk; pk.x = lo; pk.y = hi;
      *(uint2*)((char*)hS + arow * 256 + ((lcw ^ (arow & 15)) << 4) + (fq & 1) * 8) = pk;
    }
    __syncthreads();   // h ready block-wide

    // ---- second gemm: out[64][w*64..+64] += h[64][128] @ W2chunk (regs) ----
#pragma unroll
    for (int k16 = 0; k16 < 4; ++k16) {
#pragma unroll
      for (int i = 0; i < 4; ++i) {
        int r = i * 16 + fr;
        bf16x8 ah = *(const bf16x8*)((const char*)hS + r * 256 +
                                     (((k16 * 4 + fq) ^ (r & 15)) << 4));
#pragma unroll
        for (int j = 0; j < 4; ++j) acc2[i][j] = mfma16(ah, w2c[k16][j], acc2[i][j]);
      }
    }
    __syncthreads();   // h consumed before next chunk overwrites
  }

  // epilogue: dout += acc2 + b2 (each element exactly once; own rows only)
#pragma unroll
  for (int i = 0; i < 4; ++i)
#pragma unroll
    for (int j = 0; j < 4; ++j) {
      int row = row0 + i * 16 + fq * 4;
      int col = w * 64 + j * 16 + fr;
#pragma unroll
      for (int r = 0; r < 4; ++r)
        dout[(size_t)(row + r) * 512 + col] += acc2[i][j][r] + b2[col];
    }
}

// ---------------- K global max (per-wave, no LDS staging) ----------------
__launch_bounds__(256)
__global__ void kmax_kernel(const u16* __restrict__ kv, const u16* __restrict__ projf,
                            u32* __restrict__ maxslot) {
  __shared__ float wred[4];
  int bid = blockIdx.x;
  int bh = bid >> 6, nt = bid & 63;
  int b = bh >> 3, h = bh & 7;
  int n0 = nt * 64;
  int t = threadIdx.x, lane = t & 63, w = t >> 6;
  int fr = lane & 15, fq = lane >> 4;

  const u16* krow = kv + ((size_t)(b * NSEQ + n0 + w * 16 + fr)) * KVLD + h * 64;
  bf16x8 a0 = *(const bf16x8*)(krow + fq * 8);
  bf16x8 a1 = *(const bf16x8*)(krow + 32 + fq * 8);

  const bf16x8* pf = (const bf16x8*)projf;
  float m = -1e30f;
#pragma unroll
  for (int f = 0; f < 18; ++f) {
    bf16x8 b0 = pf[(f * 2 + 0) * 64 + lane];
    bf16x8 b1 = pf[(f * 2 + 1) * 64 + lane];
    f32x4 z = {0.f, 0.f, 0.f, 0.f};
    z = mfma16(a0, b0, z);
    z = mfma16(a1, b1, z);
    if (f * 16 + fr < MREAL) {
#pragma unroll
      for (int r = 0; r < 4; ++r) m = fmaxf(m, z[r]);
    }
  }
#pragma unroll
  for (int mk = 1; mk < 64; mk <<= 1) m = fmaxf(m, __shfl_xor(m, mk, 64));
  if (lane == 0) wred[w] = m;
  __syncthreads();
  if (t == 0) {
    float mm = fmaxf(fmaxf(wred[0], wred[1]), fmaxf(wred[2], wred[3]));
    u32 u = __float_as_uint(mm);
    u32 enc = (u & 0x80000000u) ? ~u : (u | 0x80000000u);
    atomicMax(maxslot, enc);
  }
}

// ------- fused ctx v3: kp features + kp^T @ [v | 1 | 0], 512 threads -------
__launch_bounds__(512)
__global__ void fused_ctx(const u16* __restrict__ kvbuf, const u16* __restrict__ projf,
                          const u32* __restrict__ maxslot, float* __restrict__ part) {
  __shared__ __align__(16) u16 kt[2][64 * 64]; // [n][dh] swizzled dbuf 16K
  __shared__ __align__(16) u16 kpL[MP * 64];   // [m][n] swizzled      36K
  __shared__ __align__(16) u16 vL[DHP * 64];   // [d][n] swizzled      12K
  int bid = blockIdx.x;
  int bh = bid >> 2, s = bid & 3;
  int b = bh >> 3, h = bh & 7;
  int t = threadIdx.x, lane = t & 63, w = t >> 6;
  int fr = lane & 15, fq = lane >> 4;
  int rg = w & 3, fh = w >> 2;           // feature-phase split
  int wq4 = w >> 1, wn = w & 1;          // gemm-phase split
  int i_base = (wq4 < 2) ? wq4 * 5 : 10 + (wq4 - 2) * 4;
  int i_cnt = (wq4 < 2) ? 5 : 4;

  if (t < 256) {  // vL rows 64..95: row 64 = ones, rest zero
    int rr = 64 + (t >> 3), sg = t & 7;
    u16 val = (rr == 64) ? (u16)0x3F80 : (u16)0;
    uint4 v4; u16* pv = (u16*)&v4;
#pragma unroll
    for (int e = 0; e < 8; ++e) pv[e] = val;
    *(uint4*)(vL + rr * 64 + sg * 8) = v4;
  }
  u32 enc = *maxslot;
  float gmax = __uint_as_float((enc & 0x80000000u) ? (enc & 0x7FFFFFFFu) : ~enc);
  const bf16x8* pf = (const bf16x8*)projf;

  bf16x8 pfr0[9], pfr1[9];
#pragma unroll
  for (int ff = 0; ff < 9; ++ff) {
    pfr0[ff] = pf[((fh * 9 + ff) * 2 + 0) * 64 + lane];
    pfr1[ff] = pf[((fh * 9 + ff) * 2 + 1) * 64 + lane];
  }

  f32x4 acc[5][3];
#pragma unroll
  for (int i = 0; i < 5; ++i)
#pragma unroll
    for (int j = 0; j < 3; ++j) acc[i][j] = f32x4{0.f, 0.f, 0.f, 0.f};

  int str = t >> 3;
  int sch = (t & 7) ^ (str & 7);
  int vr0 = t >> 4, vsg = t & 15;
  uint2 vra, vrb;

#define KT_LOAD(ci, n0)                                                        \
  gload_lds16(kvbuf + ((size_t)(b * NSEQ + (n0) + str)) * KVLD + h * 64 + sch * 8, \
              (char*)kt[ci] + t * 16)
#define V_LOAD(n0)                                                             \
  do {                                                                         \
    vra = *(const uint2*)(kvbuf + ((size_t)(b * NSEQ + (n0) + vr0)) * KVLD + 512 + h * 64 + vsg * 4); \
    vrb = *(const uint2*)(kvbuf + ((size_t)(b * NSEQ + (n0) + vr0 + 32)) * KVLD + 512 + h * 64 + vsg * 4); \
  } while (0)

  KT_LOAD(0, s * 1024);
  V_LOAD(s * 1024);
  int cur = 0;

  for (int tile = 0; tile < 16; ++tile) {
    int n0 = s * 1024 + tile * 64;
    WAITVM(0);

    {
      u16* pv = (u16*)&vra;
#pragma unroll
      for (int e = 0; e < 4; ++e) {
        int d = vsg * 4 + e, ch = (vr0 >> 3) ^ (d & 7);
        ((u16*)((char*)vL + d * 128 + ch * 16))[vr0 & 7] = pv[e];
      }
      u16* pw = (u16*)&vrb;
      int r2 = vr0 + 32;
#pragma unroll
      for (int e = 0; e < 4; ++e) {
        int d = vsg * 4 + e, ch = (r2 >> 3) ^ (d & 7);
        ((u16*)((char*)vL + d * 128 + ch * 16))[r2 & 7] = pw[e];
      }
    }
    if (tile < 15) { KT_LOAD(cur ^ 1, n0 + 64); V_LOAD(n0 + 64); }
    asm volatile("s_waitcnt lgkmcnt(0)" ::: "memory");
    __builtin_amdgcn_s_barrier();

    int rowa = rg * 16 + fr;
    bf16x8 a0 = *(const bf16x8*)((const char*)kt[cur] + rowa * 128 +
                                 ((fq ^ (fr & 7)) << 4));
    bf16x8 a1 = *(const bf16x8*)((const char*)kt[cur] + rowa * 128 +
                                 (((4 + fq) ^ (fr & 7)) << 4));

    float ss = 0.f;
#pragma unroll
    for (int e = 0; e < 8; ++e) {
      float x0 = bf2f((u16)a0[e]), x1 = bf2f((u16)a1[e]);
      ss += x0 * x0 + x1 * x1;
    }
    ss += __shfl_xor(ss, 16, 64);
    ss += __shfl_xor(ss, 32, 64);
    float dgv[4];
#pragma unroll
    for (int r4 = 0; r4 < 4; ++r4)
      dgv[r4] = __shfl(ss, fq * 4 + r4, 64) * HALF_DN2;

#pragma unroll
    for (int ff = 0; ff < 9; ++ff) {
      int f = fh * 9 + ff;
      f32x4 z = {0.f, 0.f, 0.f, 0.f};
      z = mfma16(a0, pfr0[ff], z);
      z = mfma16(a1, pfr1[ff], z);
      int col = f * 16 + fr;
      bool ok = col < MREAL;
      float k0v = ok ? (__expf(z[0] - dgv[0] - gmax) + KEPS) : 0.f;
      float k1v = ok ? (__expf(z[1] - dgv[1] - gmax) + KEPS) : 0.f;
      float k2v = ok ? (__expf(z[2] - dgv[2] - gmax) + KEPS) : 0.f;
      float k3v = ok ? (__expf(z[3] - dgv[3] - gmax) + KEPS) : 0.f;
      u32 lo, hi;
      asm("v_cvt_pk_bf16_f32 %0, %1, %2" : "=v"(lo) : "v"(k0v), "v"(k1v));
      asm("v_cvt_pk_bf16_f32 %0, %1, %2" : "=v"(hi) : "v"(k2v), "v"(k3v));
      uint2 pk2; pk2.x = lo; pk2.y = hi;
      int ch = (rg * 2 + (fq >> 1)) ^ (fr & 7);
      *(uint2*)((char*)kpL + col * 128 + ch * 16 + (fq & 1) * 8) = pk2;
    }
    asm volatile("s_waitcnt lgkmcnt(0)" ::: "memory");
    __builtin_amdgcn_s_barrier();

#pragma unroll
    for (int kc = 0; kc < 2; ++kc) {
      int rch = ((kc * 4 + fq) ^ (fr & 7)) << 4;
      bf16x8 av[5], bv[3];
#pragma unroll
      for (int i = 0; i < 5; ++i)
        if (i < i_cnt)
          av[i] = *(const bf16x8*)((const char*)kpL + ((i_base + i) * 16 + fr) * 128 + rch);
#pragma unroll
      for (int j = 0; j < 3; ++j)
        bv[j] = *(const bf16x8*)((const char*)vL + (wn * 48 + j * 16 + fr) * 128 + rch);
#pragma unroll
      for (int i = 0; i < 5; ++i)
        if (i < i_cnt)
#pragma unroll
          for (int j = 0; j < 3; ++j) acc[i][j] = mfma16(av[i], bv[j], acc[i][j]);
    }
    asm volatile("s_waitcnt lgkmcnt(0)" ::: "memory");
    __builtin_amdgcn_s_barrier();
    cur ^= 1;
  }
#undef KT_LOAD
#undef V_LOAD

  float* dst = part + ((size_t)bh * 4 + s) * MP * DHP;
#pragma unroll
  for (int i = 0; i < 5; ++i)
    if (i < i_cnt)
#pragma unroll
      for (int j = 0; j < 3; ++j) {
        int m = (i_base + i) * 16 + fq * 4;
        int c = wn * 48 + j * 16 + fr;
#pragma unroll
        for (int r = 0; r < 4; ++r) dst[(size_t)(m + r) * DHP + c] = acc[i][j][r];
      }
}

__launch_bounds__(256)
__global__ void ctx_reduce2(const float* __restrict__ part, u16* __restrict__ ctxT) {
  int bh = blockIdx.x, t = threadIdx.x;
  const float* p = part + (size_t)bh * 4 * MP * DHP;
  u16* dst = ctxT + (size_t)bh * DHP * MP;
  for (int idx = t; idx < DHP * MP; idx += 256) {
    int d = idx / MP, m = idx - d * MP;
    size_t o = (size_t)m * DHP + d;
    float v = p[o] + p[o + MP * DHP] + p[o + 2 * MP * DHP] + p[o + 3 * MP * DHP];
    dst[idx] = f2bf(v);   // ctxT[d][m] = ctx[m][d]
  }
}

// -- fused attn v4 (R5-verified): swapped feature MFMA + packed b64 qp writes,
//    qt XOR-swizzle, phase-2 bv distance-1 prefetch.
__launch_bounds__(256)
__global__ void fused_attn(const u16* __restrict__ qb, const u16* __restrict__ ctxT,
                           const u16* __restrict__ projf, u16* __restrict__ attnb) {
  __shared__ __align__(16) u16 qt[64 * 64];    // swizzled; reused as ob later
  __shared__ __align__(16) u16 qpL[64 * MPP];  // [n][m] padded stride
  __shared__ float dbuf[64];
  int bid = blockIdx.x;
  int bh = bid >> 6, nt = bid & 63;
  int b = bh >> 3, h = bh & 7;
  int n0 = nt * 64;
  int t = threadIdx.x, lane = t & 63, w = t >> 6;
  int wm = w >> 1, wn = w & 1;
  int fr = lane & 15, fq = lane >> 4;

#pragma unroll
  for (int it = 0; it < 4; ++it) {
    int idx = t + it * 256;
    int r = idx >> 4, sg = idx & 15;
    int dst = (r * 128 + sg * 8) ^ ((r & 7) << 4);
    *(uint2*)((char*)qt + dst) =
        *(const uint2*)(qb + ((size_t)(b * NSEQ + n0 + r)) * KVLD + h * 64 + sg * 4);
  }
  __syncthreads();

  int swz = (fr & 7) << 4;
  bf16x8 a0 = *(const bf16x8*)((const char*)qt +
                               (((w * 16 + fr) * 128 + fq * 16) ^ swz));
  bf16x8 a1 = *(const bf16x8*)((const char*)qt +
                               (((w * 16 + fr) * 128 + 64 + fq * 16) ^ swz));

  float ss = 0.f;
#pragma unroll
  for (int e = 0; e < 8; ++e) {
    float x0 = bf2f((u16)a0[e]), x1 = bf2f((u16)a1[e]);
    ss += x0 * x0 + x1 * x1;
  }
  ss += __shfl_xor(ss, 16, 64);
  ss += __shfl_xor(ss, 32, 64);
  float dg = ss * HALF_DN2;

  const bf16x8* pf = (const bf16x8*)projf;
  f32x4 accf[18];
#pragma unroll
  for (int f = 0; f < 18; ++f) {
    f32x4 z = {0.f, 0.f, 0.f, 0.f};
    z = mfma16(pf[(f * 2 + 0) * 64 + lane], a0, z);
    z = mfma16(pf[(f * 2 + 1) * 64 + lane], a1, z);
    accf[f] = z;
  }
  float mm = -1e30f;
#pragma unroll
  for (int f = 0; f < 18; ++f)
#pragma unroll
    for (int r = 0; r < 4; ++r) mm = fmaxf(mm, accf[f][r]);
  mm = fmaxf(mm, __shfl_xor(mm, 16, 64));
  mm = fmaxf(mm, __shfl_xor(mm, 32, 64));

  u16* qp = qpL + (w * 16 + fr) * MPP + fq * 4;
#pragma unroll
  for (int f = 0; f < 18; ++f) {
    float e0 = __expf(accf[f][0] - dg - mm) + KEPS;
    float e1 = __expf(accf[f][1] - dg - mm) + KEPS;
    float e2 = __expf(accf[f][2] - dg - mm) + KEPS;
    float e3 = __expf(accf[f][3] - dg - mm) + KEPS;
    u32 lo, hi;
    asm("v_cvt_pk_bf16_f32 %0, %1, %2" : "=v"(lo) : "v"(e0), "v"(e1));
    asm("v_cvt_pk_bf16_f32 %0, %1, %2" : "=v"(hi) : "v"(e2), "v"(e3));
    uint2 pk; pk.x = lo; pk.y = hi;
    *(uint2*)(qp + f * 16) = pk;
  }
  __syncthreads();

  const u16* cg = ctxT + (size_t)bh * DHP * MP;
  f32x4 acc2[2][3];
#pragma unroll
  for (int i = 0; i < 2; ++i)
#pragma unroll
    for (int j = 0; j < 3; ++j) acc2[i][j] = f32x4{0.f, 0.f, 0.f, 0.f};
  bf16x8 bvc[3];
#pragma unroll
  for (int j = 0; j < 3; ++j)
    bvc[j] = *(const bf16x8*)(cg + (size_t)(wn * 48 + j * 16 + fr) * MP + fq * 8);
#pragma unroll
  for (int kc = 0; kc < 9; ++kc) {
    bf16x8 bvn[3];
    if (kc < 8) {
#pragma unroll
      for (int j = 0; j < 3; ++j)
        bvn[j] = *(const bf16x8*)(cg + (size_t)(wn * 48 + j * 16 + fr) * MP +
                                  (kc + 1) * 32 + fq * 8);
    }
    bf16x8 av[2];
#pragma unroll
    for (int i = 0; i < 2; ++i)
      av[i] = *(const bf16x8*)(qpL + (wm * 32 + i * 16 + fr) * MPP + kc * 32 + fq * 8);
#pragma unroll
    for (int i = 0; i < 2; ++i)
#pragma unroll
      for (int j = 0; j < 3; ++j) acc2[i][j] = mfma16(av[i], bvc[j], acc2[i][j]);
    if (kc < 8) {
#pragma unroll
      for (int j = 0; j < 3; ++j) bvc[j] = bvn[j];
    }
  }
  if (wn == 1 && fr == 0) {
#pragma unroll
    for (int i = 0; i < 2; ++i) {
      int rl = wm * 32 + i * 16 + fq * 4;
#pragma unroll
      for (int r = 0; r < 4; ++r) dbuf[rl + r] = acc2[i][1][r];  // col 64 = denom
    }
  }
  __syncthreads();

  u16* ob = qt;  // reuse (qt reads all complete)
#pragma unroll
  for (int i = 0; i < 2; ++i)
#pragma unroll
    for (int j = 0; j < 3; ++j) {
      int cl = wn * 48 + j * 16 + fr;
      if (cl < 64) {
        int rl = wm * 32 + i * 16 + fq * 4;
#pragma unroll
        for (int r = 0; r < 4; ++r)
          ob[(rl + r) * 64 + cl] = f2bf(acc2[i][j][r] / dbuf[rl + r]);
      }
    }
  __syncthreads();

  u16* dst = attnb + ((size_t)(b * NSEQ + n0)) * KVLD + h * 64;
  for (int idx = t; idx < 64 * 8; idx += 256) {
    int r = idx >> 3, sg = idx & 7;
    *(uint4*)(dst + (size_t)r * KVLD + sg * 8) = *(const uint4*)(ob + r * 64 + sg * 8);
  }
}

// ---------------- workspace layout (total ~132.5 MB) ----------------
constexpr size_t OFF_WQT   = 0;                       // 512*512*2
constexpr size_t OFF_WKT   = 524288;                  // (wkt|wvt adjacent = kv weights)
constexpr size_t OFF_WVT   = 1048576;
constexpr size_t OFF_WOT   = 1572864;
constexpr size_t OFF_W1F   = 2097152;                 // 2MB: W1 frag layout
constexpr size_t OFF_W2F   = 4194304;                 // 2MB: W2 frag layout
constexpr size_t OFF_PROJF = 6328320;                 // 288*64*2 (fragment layout)
constexpr size_t OFF_MAX   = 6365184;                 // 256
constexpr size_t OFF_CTXT  = 6365440;                 // 64*96*288*2
constexpr size_t OFF_H     = 9904384;                 // 32 MB: LN1 out
constexpr size_t OFF_KV    = 43458816;                // 64 MB: [32768][1024] k|v -> q|attn
constexpr size_t OFF_PART  = 110567680;               // 64*4*288*96*4
constexpr size_t WS_NEED   = 138879232;

extern "C" void kernel_launch(void* const* d_in, const int* in_sizes, int n_in,
                              void* d_out, int out_size, void* d_ws, size_t ws_size,
                              hipStream_t stream) {
  const float* x    = (const float*)d_in[0];
  const float* w_q  = (const float*)d_in[1];
  const float* w_k  = (const float*)d_in[2];
  const float* w_v  = (const float*)d_in[3];
  const float* w_o  = (const float*)d_in[4];
  const float* b_o  = (const float*)d_in[5];
  const float* ln1g = (const float*)d_in[6];
  const float* ln1b = (const float*)d_in[7];
  const float* ln2g = (const float*)d_in[8];
  const float* ln2b = (const float*)d_in[9];
  const float* ffw1 = (const float*)d_in[10];
  const float* ffb1 = (const float*)d_in[11];
  const float* ffw2 = (const float*)d_in[12];
  const float* ffb2 = (const float*)d_in[13];
  const float* proj = (const float*)d_in[14];
  (void)in_sizes; (void)n_in; (void)out_size;

  float* dout = (float*)d_out;
  if (ws_size < WS_NEED) {  // diagnostic: absmax ~12345 => shrink workspace
    ws_sentinel<<<1, 1, 0, stream>>>(dout);
    return;
  }

  char* ws = (char*)d_ws;
  u16* wqt   = (u16*)(ws + OFF_WQT);
  u16* wkt   = (u16*)(ws + OFF_WKT);
  u16* wvt   = (u16*)(ws + OFF_WVT);
  u16* wot   = (u16*)(ws + OFF_WOT);
  u16* w1f   = (u16*)(ws + OFF_W1F);
  u16* w2f   = (u16*)(ws + OFF_W2F);
  u16* projf = (u16*)(ws + OFF_PROJF);
  u32* maxsl = (u32*)(ws + OFF_MAX);
  u16* ctxt  = (u16*)(ws + OFF_CTXT);
  u16* hbuf  = (u16*)(ws + OFF_H);    // LN1 out
  u16* kvbuf = (u16*)(ws + OFF_KV);   // [32768][1024]: k|v -> q|attn
  float* part = (float*)(ws + OFF_PART);

  hipMemsetAsync(maxsl, 0, 4, stream);

  transpose_cvt<<<256, 256, 0, stream>>>(w_q, wqt, 512, 512);
  transpose_cvt<<<256, 256, 0, stream>>>(w_k, wkt, 512, 512);
  transpose_cvt<<<256, 256, 0, stream>>>(w_v, wvt, 512, 512);
  transpose_cvt<<<256, 256, 0, stream>>>(w_o, wot, 512, 512);
  w1_prep<<<4096, 256, 0, stream>>>(ffw1, w1f);
  w2_prep<<<4096, 256, 0, stream>>>(ffw2, w2f);
  proj_prep<<<72, 256, 0, stream>>>(proj, projf);

  ln_fwd<<<8192, 256, 0, stream>>>(x, ln1g, ln1b, hbuf);
  // k|v in one GEMM (wkt/wvt stacked = 1024 output cols)
  gemm256<0><<<512, 512, 0, stream>>>(hbuf, 512, wkt, 512, 512, kvbuf, 1024, 1024, nullptr, nullptr);
  kmax_kernel<<<4096, 256, 0, stream>>>(kvbuf, projf, maxsl);
  fused_ctx<<<256, 512, 0, stream>>>(kvbuf, projf, maxsl, part);
  ctx_reduce2<<<64, 256, 0, stream>>>(part, ctxt);
  // q overwrites dead k-half (cols 0..511)
  gemm256<0><<<256, 512, 0, stream>>>(hbuf, 512, wqt, 512, 512, kvbuf, 512, 1024, nullptr, nullptr);
  // attn overwrites dead v-half (cols 512..1023)
  fused_attn<<<4096, 256, 0, stream>>>(kvbuf, ctxt, projf, kvbuf + 512);
  gemm256<1><<<256, 512, 0, stream>>>(kvbuf + 512, 1024, wot, 512, 512, dout, 512, 512, b_o, x);
  // fused FFN v7: LN2 + dout += gelu(LN2(dout) @ W1 + b1) @ W2 + b2
  ffn_fused<<<512, 512, 0, stream>>>(dout, ln2g, ln2b, w1f, w2f, ffb1, ffb2);
}

// Round 20
// 547.865 us; speedup vs baseline: 1.0247x; 1.0247x over previous
//
#include <hip/hip_runtime.h>
#include <cmath>

typedef unsigned short u16;
typedef unsigned int u32;
typedef short bf16x8 __attribute__((ext_vector_type(8)));
typedef float f32x4 __attribute__((ext_vector_type(4)));

#define DEVI __device__ __forceinline__

constexpr int NSEQ = 4096, DIMM = 512;
constexpr int KVLD = 1024;   // kv combined row stride
constexpr int MP = 288;      // padded feature dim (266 -> 18*16)
constexpr int MPP = 296;     // qpL LDS row stride (bank-conflict-free)
constexpr int MREAL = 266;
constexpr int DHP = 96;      // 64 v-cols + ones col + zero pad
constexpr float LNEPS = 1e-5f;
constexpr float KEPS = 1e-4f;
constexpr float DN = 0.3535533905932738f;      // 64^-0.25
constexpr float HALF_DN2 = 0.0625f;            // 0.5 * 64^-0.5

DEVI u16 f2bf(float f) {
  u32 u = __float_as_uint(f);
  u32 r = (u + 0x7FFFu + ((u >> 16) & 1u)) >> 16;
  return (u16)r;
}
DEVI float bf2f(u16 h) { return __uint_as_float(((u32)h) << 16); }

DEVI f32x4 mfma16(bf16x8 a, bf16x8 b, f32x4 c) {
  return __builtin_amdgcn_mfma_f32_16x16x32_bf16(a, b, c, 0, 0, 0);
}

DEVI void gload_lds16(const void* g, void* l) {
  __builtin_amdgcn_global_load_lds(
      (const __attribute__((address_space(1))) u32*)g,
      (__attribute__((address_space(3))) u32*)l, 16, 0, 0);
}

// tanh-form GELU: z * e/(e+1), e = exp(1.5957691*(z + 0.044715 z^3))
DEVI float gelu_fast(float z) {
  float a = fminf(1.5957691216057308f * (z + 0.044715f * z * z * z), 60.f);
  float e = __expf(a);
  return z * e * __builtin_amdgcn_rcpf(e + 1.f);
}

// ---------------- diagnostics ----------------
__global__ void ws_sentinel(float* out) { out[0] = 12345.0f; }

// ---------------- weight prep ----------------
__launch_bounds__(256)
__global__ void transpose_cvt(const float* __restrict__ in, u16* __restrict__ out,
                              int K, int Nn) {
  __shared__ float tl[32][33];
  int ntn = Nn >> 5;
  int bid = blockIdx.x;
  int kt = bid / ntn, ntt = bid - kt * ntn;
  int k0 = kt << 5, nn0 = ntt << 5;
  int t = threadIdx.x;
  int r = t >> 5, c = t & 31;
#pragma unroll
  for (int i = 0; i < 4; ++i)
    tl[r + i * 8][c] = in[(size_t)(k0 + r + i * 8) * Nn + nn0 + c];
  __syncthreads();
#pragma unroll
  for (int i = 0; i < 4; ++i)
    out[(size_t)(nn0 + r + i * 8) * K + k0 + c] = f2bf(tl[c][r + i * 8]);
}

// projf: B-fragment layout [f][half][lane][8] for direct register loads
__global__ void proj_prep(const float* __restrict__ proj, u16* __restrict__ projf) {
  int idx = blockIdx.x * 256 + threadIdx.x;
  if (idx >= MP * 64) return;
  int e = idx & 7, lane = (idx >> 3) & 63, fh = idx >> 9;
  int f = fh >> 1, half = fh & 1;
  int m = f * 16 + (lane & 15);
  int d = half * 32 + (lane >> 4) * 8 + e;
  float v = (m < MREAL) ? proj[m * 64 + d] * DN : 0.f;
  projf[idx] = f2bf(v);
}

// w1f: A-operand fragment layout [hcolf(128)][k16(16)][lane][8]
//   value = W1[k][hcol], hcol = hcolf*16 + (lane&15), k = k16*32 + (lane>>4)*8 + e
__global__ void w1_prep(const float* __restrict__ w1, u16* __restrict__ w1f) {
  int idx = blockIdx.x * 256 + threadIdx.x;   // < 128*16*512 = 1048576
  int e = idx & 7, lane = (idx >> 3) & 63;
  int k16 = (idx >> 9) & 15, hcf = idx >> 13;
  int hcol = hcf * 16 + (lane & 15);
  int k = k16 * 32 + (lane >> 4) * 8 + e;
  w1f[idx] = f2bf(w1[(size_t)k * 2048 + hcol]);
}

// w2f: B-operand fragment layout [ocolf(32)][hk16(64)][lane][8]
//   value = W2[hk][ocol], ocol = ocolf*16 + (lane&15), hk = hk16*32 + (lane>>4)*8 + e
__global__ void w2_prep(const float* __restrict__ w2, u16* __restrict__ w2f) {
  int idx = blockIdx.x * 256 + threadIdx.x;   // < 32*64*512 = 1048576
  int e = idx & 7, lane = (idx >> 3) & 63;
  int hk16 = (idx >> 9) & 63, ocf = idx >> 15;
  int ocol = ocf * 16 + (lane & 15);
  int hk = hk16 * 32 + (lane >> 4) * 8 + e;
  w2f[idx] = f2bf(w2[(size_t)hk * 512 + ocol]);
}

// ---------------- layernorm (one wave per row) ----------------
__launch_bounds__(256)
__global__ void ln_fwd(const float* __restrict__ x, const float* __restrict__ g,
                       const float* __restrict__ bt, u16* __restrict__ out) {
  int w = threadIdx.x >> 6, lane = threadIdx.x & 63;
  int row = blockIdx.x * 4 + w;
  const float* xr = x + (size_t)row * DIMM;
  int c0 = lane * 4;
  float4 v0 = *(const float4*)(xr + c0);
  float4 v1 = *(const float4*)(xr + 256 + c0);
  float s = v0.x + v0.y + v0.z + v0.w + v1.x + v1.y + v1.z + v1.w;
  float sq = v0.x * v0.x + v0.y * v0.y + v0.z * v0.z + v0.w * v0.w +
             v1.x * v1.x + v1.y * v1.y + v1.z * v1.z + v1.w * v1.w;
#pragma unroll
  for (int mk = 1; mk < 64; mk <<= 1) {
    s += __shfl_xor(s, mk, 64);
    sq += __shfl_xor(sq, mk, 64);
  }
  float mu = s * (1.f / 512.f);
  float var = sq * (1.f / 512.f) - mu * mu;
  float rstd = rsqrtf(var + LNEPS);
  float4 g0 = *(const float4*)(g + c0);
  float4 g1 = *(const float4*)(g + 256 + c0);
  float4 b0 = *(const float4*)(bt + c0);
  float4 b1 = *(const float4*)(bt + 256 + c0);
  u16* orow = out + (size_t)row * DIMM;
  uint2 p0, p1;
  {
    u16 h0 = f2bf((v0.x - mu) * rstd * g0.x + b0.x);
    u16 h1 = f2bf((v0.y - mu) * rstd * g0.y + b0.y);
    u16 h2 = f2bf((v0.z - mu) * rstd * g0.z + b0.z);
    u16 h3 = f2bf((v0.w - mu) * rstd * g0.w + b0.w);
    p0.x = ((u32)h1 << 16) | h0; p0.y = ((u32)h3 << 16) | h2;
  }
  {
    u16 h0 = f2bf((v1.x - mu) * rstd * g1.x + b1.x);
    u16 h1 = f2bf((v1.y - mu) * rstd * g1.y + b1.y);
    u16 h2 = f2bf((v1.z - mu) * rstd * g1.z + b1.z);
    u16 h3 = f2bf((v1.w - mu) * rstd * g1.w + b1.w);
    p1.x = ((u32)h1 << 16) | h0; p1.y = ((u32)h3 << 16) | h2;
  }
  *(uint2*)(orow + c0) = p0;
  *(uint2*)(orow + 256 + c0) = p1;
}

// -- 256x256 bf16 GEMM, BK=64, 512 threads (8 waves, 2Mx4N), dbuf LDS 128KB.
//    R7 v3 schedule (best measured): 24 fragments up front; half MFMAs;
//    lgkmcnt(0)+sched_barrier+barrier; stage; remaining MFMAs overlap flight.
// EPI: 0 = bf16 out; 1 = fp32 out + bias + residual
#define WAITVM(N) asm volatile("s_waitcnt vmcnt(" #N ")" ::: "memory")

template <int EPI>
__launch_bounds__(512)
__global__ void gemm256(const u16* __restrict__ A, int lda,
                        const u16* __restrict__ Bt, int ldb, int K,
                        void* __restrict__ OutP, int Nout, int ldo,
                        const float* __restrict__ bias,
                        const float* __restrict__ Res) {
  __shared__ __align__(16) u16 Al[2][256 * 64];
  __shared__ __align__(16) u16 Bl[2][256 * 64];
  int ntiles = Nout >> 8;
  int nwg = gridDim.x;
  int bid = blockIdx.x;
  int cpx = nwg >> 3;                       // grids are multiples of 8
  int wg = (bid & 7) * cpx + (bid >> 3);    // XCD swizzle (bijective: nwg%8==0)
  int mt = wg / ntiles, nt = wg - mt * ntiles;
  int t = threadIdx.x, lane = t & 63, w = t >> 6;
  int wm = w >> 2, wn = w & 3;              // wave grid 2M x 4N
  int fr = lane & 15, fq = lane >> 4;
  int rowA0 = mt * 256, colB0 = nt * 256;
  int swz = (fr & 7) << 4;                  // read-side XOR (row&7 == fr&7)

  f32x4 acc[8][4];
#pragma unroll
  for (int i = 0; i < 8; ++i)
#pragma unroll
    for (int j = 0; j < 4; ++j) acc[i][j] = f32x4{0.f, 0.f, 0.f, 0.f};

  int srow = t >> 3;                                   // 0..63
  int so = ((t * 16) & 127) ^ ((srow & 7) << 4);       // swizzled in-row byte

#define STAGE_G(bufi, k0)                                                       \
  do {                                                                          \
    _Pragma("unroll") for (int it = 0; it < 4; ++it) {                          \
      gload_lds16(                                                              \
          (const char*)(A + ((size_t)(rowA0 + srow + it * 64) * lda + (k0))) + so, \
          (char*)Al[bufi] + t * 16 + it * 8192);                                \
      gload_lds16(                                                              \
          (const char*)(Bt + ((size_t)(colB0 + srow + it * 64) * ldb + (k0))) + so, \
          (char*)Bl[bufi] + t * 16 + it * 8192);                                \
    }                                                                           \
  } while (0)

  int NT = K >> 6;
  STAGE_G(0, 0);
  STAGE_G(1, 64);
  int bi = 0;
  for (int tt = 0; tt < NT; ++tt) {
    if (tt + 1 < NT) { WAITVM(8); } else { WAITVM(0); }
    __builtin_amdgcn_s_barrier();   // all waves: stage tt visible in LDS

    bf16x8 av[8][2], bv[4][2];
#pragma unroll
    for (int i = 0; i < 8; ++i)
#pragma unroll
      for (int ks = 0; ks < 2; ++ks) {
        int row = wm * 128 + i * 16 + fr;
        av[i][ks] = *(const bf16x8*)((const char*)Al[bi] + row * 128 +
                                     (((ks << 6) | (fq << 4)) ^ swz));
      }
#pragma unroll
    for (int j = 0; j < 4; ++j)
#pragma unroll
      for (int ks = 0; ks < 2; ++ks) {
        int row = wn * 64 + (j)*16 + fr;
        bv[j][ks] = *(const bf16x8*)((const char*)Bl[bi] + row * 128 +
                                     (((ks << 6) | (fq << 4)) ^ swz));
      }

    __builtin_amdgcn_s_setprio(1);
#pragma unroll
    for (int i = 0; i < 4; ++i)
#pragma unroll
      for (int j = 0; j < 4; ++j)
#pragma unroll
        for (int ks = 0; ks < 2; ++ks)
          acc[i][j] = mfma16(av[i][ks], bv[j][ks], acc[i][j]);
    __builtin_amdgcn_s_setprio(0);

    asm volatile("s_waitcnt lgkmcnt(0)" ::: "memory");
    __builtin_amdgcn_sched_barrier(0);
    __builtin_amdgcn_s_barrier();
    if (tt + 2 < NT) STAGE_G(bi, (tt + 2) * 64);

    __builtin_amdgcn_s_setprio(1);
#pragma unroll
    for (int i = 4; i < 8; ++i)
#pragma unroll
      for (int j = 0; j < 4; ++j)
#pragma unroll
        for (int ks = 0; ks < 2; ++ks)
          acc[i][j] = mfma16(av[i][ks], bv[j][ks], acc[i][j]);
    __builtin_amdgcn_s_setprio(0);
    bi ^= 1;
  }
#undef STAGE_G

#pragma unroll
  for (int i = 0; i < 8; ++i)
#pragma unroll
    for (int j = 0; j < 4; ++j) {
      int row = rowA0 + wm * 128 + i * 16 + fq * 4;
      int col = colB0 + wn * 64 + j * 16 + fr;
#pragma unroll
      for (int r = 0; r < 4; ++r) {
        float v = acc[i][j][r];
        size_t idx = (size_t)(row + r) * ldo + col;
        if constexpr (EPI == 0) {
          ((u16*)OutP)[idx] = f2bf(v);
        } else {
          ((float*)OutP)[idx] = v + bias[col] + Res[(size_t)(row + r) * 512 + col];
        }
      }
    }
}

// -- fused FFN v6 (R18-measured-best, 548.2us total): LN2 fused into staging +
//    w1-only register prefetch. w2 prefetch closed permanently (R16/R19: the
//    512-thread VGPR cap of 128 is immovable; dual prefetch defeats w1's).
__launch_bounds__(512)
__global__ void ffn_fused(float* __restrict__ dout, const float* __restrict__ ln2g,
                          const float* __restrict__ ln2b,
                          const u16* __restrict__ w1f, const u16* __restrict__ w2f,
                          const float* __restrict__ b1, const float* __restrict__ b2) {
  __shared__ __align__(16) u16 As[64 * 512];    // 64 KB, 8-chunk swizzle
  __shared__ __align__(16) u16 hS[64 * 128];    // 16 KB, 16-chunk swizzle
  int nwg = gridDim.x;                          // 512
  int bid = blockIdx.x;
  int cpx = nwg >> 3;
  int wg = (bid & 7) * cpx + (bid >> 3);        // XCD swizzle
  int row0 = wg * 64;
  int t = threadIdx.x, lane = t & 63, w = t >> 6;
  int fr = lane & 15, fq = lane >> 4;

  // prologue: issue chunk 0's w1 fragment loads FIRST (latency hides under LN)
  bf16x8 w1c[16];
  {
    const u16* w1p = w1f + ((size_t)(0 * 8 + w) * 16) * 512 + lane * 8;
#pragma unroll
    for (int kk = 0; kk < 16; ++kk) w1c[kk] = *(const bf16x8*)(w1p + kk * 512);
  }

  // fused LN2 staging: wave w normalizes rows w*8 .. w*8+7 into As (swizzled)
  {
    int c0 = lane * 4;
    float4 g0 = *(const float4*)(ln2g + c0);
    float4 g1 = *(const float4*)(ln2g + 256 + c0);
    float4 b0 = *(const float4*)(ln2b + c0);
    float4 b1v = *(const float4*)(ln2b + 256 + c0);
    int lc0 = lane >> 1, half = (lane & 1) * 8;
#pragma unroll
    for (int rr8 = 0; rr8 < 8; ++rr8) {
      int rr = w * 8 + rr8;
      const float* xr = dout + (size_t)(row0 + rr) * 512;
      float4 v0 = *(const float4*)(xr + c0);
      float4 v1 = *(const float4*)(xr + 256 + c0);
      float s = v0.x + v0.y + v0.z + v0.w + v1.x + v1.y + v1.z + v1.w;
      float sq = v0.x * v0.x + v0.y * v0.y + v0.z * v0.z + v0.w * v0.w +
                 v1.x * v1.x + v1.y * v1.y + v1.z * v1.z + v1.w * v1.w;
#pragma unroll
      for (int mk = 1; mk < 64; mk <<= 1) {
        s += __shfl_xor(s, mk, 64);
        sq += __shfl_xor(sq, mk, 64);
      }
      float mu = s * (1.f / 512.f);
      float var = sq * (1.f / 512.f) - mu * mu;
      float rstd = rsqrtf(var + LNEPS);
      uint2 p0, p1;
      {
        u16 h0 = f2bf((v0.x - mu) * rstd * g0.x + b0.x);
        u16 h1 = f2bf((v0.y - mu) * rstd * g0.y + b0.y);
        u16 h2 = f2bf((v0.z - mu) * rstd * g0.z + b0.z);
        u16 h3 = f2bf((v0.w - mu) * rstd * g0.w + b0.w);
        p0.x = ((u32)h1 << 16) | h0; p0.y = ((u32)h3 << 16) | h2;
      }
      {
        u16 h0 = f2bf((v1.x - mu) * rstd * g1.x + b1v.x);
        u16 h1 = f2bf((v1.y - mu) * rstd * g1.y + b1v.y);
        u16 h2 = f2bf((v1.z - mu) * rstd * g1.z + b1v.z);
        u16 h3 = f2bf((v1.w - mu) * rstd * g1.w + b1v.w);
        p1.x = ((u32)h1 << 16) | h0; p1.y = ((u32)h3 << 16) | h2;
      }
      // logical chunk lc holds cols [lc*8, lc*8+8); physical = lc ^ (rr&7)
      *(uint2*)((char*)As + rr * 1024 + ((lc0 ^ (rr & 7)) << 4) + half) = p0;
      *(uint2*)((char*)As + rr * 1024 + (((32 + lc0) ^ (rr & 7)) << 4) + half) = p1;
    }
  }

  f32x4 acc2[4][4];
#pragma unroll
  for (int i = 0; i < 4; ++i)
#pragma unroll
    for (int j = 0; j < 4; ++j) acc2[i][j] = f32x4{0.f, 0.f, 0.f, 0.f};

  __syncthreads();   // As (ds_writes) visible block-wide

  for (int ch = 0; ch < 16; ++ch) {
    // ---- first gemm: wave w computes hcols [ch*128+w*16, +16) x rows 0..63
    f32x4 acch[4];
#pragma unroll
    for (int i = 0; i < 4; ++i) acch[i] = f32x4{0.f, 0.f, 0.f, 0.f};
#pragma unroll
    for (int kk = 0; kk < 16; ++kk) {
      bf16x8 av = w1c[kk];
#pragma unroll
      for (int i = 0; i < 4; ++i) {
        int r = i * 16 + fr;
        bf16x8 bv = *(const bf16x8*)((const char*)As + r * 1024 +
                                     (((kk * 4 + fq) ^ (r & 7)) << 4));
        acch[i] = mfma16(av, bv, acch[i]);
      }
    }
    // w1c dead -> prefetch next chunk's w1 into the same registers now;
    // loads overlap the pack + barrier + entire second gemm.
    if (ch + 1 < 16) {
      const u16* w1p = w1f + ((size_t)((ch + 1) * 8 + w) * 16) * 512 + lane * 8;
#pragma unroll
      for (int kk = 0; kk < 16; ++kk) w1c[kk] = *(const bf16x8*)(w1p + kk * 512);
    }
    // gelu(. + b1) + cvt_pk pack + swizzled b64 write into hS
    float bb0 = b1[ch * 128 + w * 16 + fq * 4 + 0];
    float bb1 = b1[ch * 128 + w * 16 + fq * 4 + 1];
    float bb2 = b1[ch * 128 + w * 16 + fq * 4 + 2];
    float bb3 = b1[ch * 128 + w * 16 + fq * 4 + 3];
    int lcw = w * 2 + (fq >> 1);                // logical 16B chunk in 256B row
#pragma unroll
    for (int i = 0; i < 4; ++i) {
      int arow = i * 16 + fr;
      float g0 = gelu_fast(acch[i][0] + bb0);
      float g1 = gelu_fast(acch[i][1] + bb1);
      float g2 = gelu_fast(acch[i][2] + bb2);
      float g3 = gelu_fast(acch[i][3] + bb3);
      u32 lo, hi;
      asm("v_cvt_pk_bf16_f32 %0, %1, %2" : "=v"(lo) : "v"(g0), "v"(g1));
      asm("v_cvt_pk_bf16_f32 %0, %1, %2" : "=v"(hi) : "v"(g2), "v"(g3));
      uint2 pk; pk.x = lo; pk.y = hi;
      *(uint2*)((char*)hS + arow * 256 + ((lcw ^ (arow & 15)) << 4) + (fq & 1) * 8) = pk;
    }
    __syncthreads();   // h ready block-wide

    // ---- second gemm: out[64][w*64..+64] += h[64][128] @ W2chunk ----
#pragma unroll
    for (int k16 = 0; k16 < 4; ++k16) {
      bf16x8 bw[4];
#pragma unroll
      for (int j = 0; j < 4; ++j)
        bw[j] = *(const bf16x8*)(w2f +
                 ((size_t)((w * 4 + j) * 64 + ch * 4 + k16)) * 512 + lane * 8);
#pragma unroll
      for (int i = 0; i < 4; ++i) {
        int r = i * 16 + fr;
        bf16x8 ah = *(const bf16x8*)((const char*)hS + r * 256 +
                                     (((k16 * 4 + fq) ^ (r & 15)) << 4));
#pragma unroll
        for (int j = 0; j < 4; ++j) acc2[i][j] = mfma16(ah, bw[j], acc2[i][j]);
      }
    }
    __syncthreads();   // h consumed before next chunk overwrites
  }

  // epilogue: dout += acc2 + b2 (each element exactly once; own rows only)
#pragma unroll
  for (int i = 0; i < 4; ++i)
#pragma unroll
    for (int j = 0; j < 4; ++j) {
      int row = row0 + i * 16 + fq * 4;
      int col = w * 64 + j * 16 + fr;
#pragma unroll
      for (int r = 0; r < 4; ++r)
        dout[(size_t)(row + r) * 512 + col] += acc2[i][j][r] + b2[col];
    }
}

// ---------------- K global max (per-wave, no LDS staging) ----------------
__launch_bounds__(256)
__global__ void kmax_kernel(const u16* __restrict__ kv, const u16* __restrict__ projf,
                            u32* __restrict__ maxslot) {
  __shared__ float wred[4];
  int bid = blockIdx.x;
  int bh = bid >> 6, nt = bid & 63;
  int b = bh >> 3, h = bh & 7;
  int n0 = nt * 64;
  int t = threadIdx.x, lane = t & 63, w = t >> 6;
  int fr = lane & 15, fq = lane >> 4;

  const u16* krow = kv + ((size_t)(b * NSEQ + n0 + w * 16 + fr)) * KVLD + h * 64;
  bf16x8 a0 = *(const bf16x8*)(krow + fq * 8);
  bf16x8 a1 = *(const bf16x8*)(krow + 32 + fq * 8);

  const bf16x8* pf = (const bf16x8*)projf;
  float m = -1e30f;
#pragma unroll
  for (int f = 0; f < 18; ++f) {
    bf16x8 b0 = pf[(f * 2 + 0) * 64 + lane];
    bf16x8 b1 = pf[(f * 2 + 1) * 64 + lane];
    f32x4 z = {0.f, 0.f, 0.f, 0.f};
    z = mfma16(a0, b0, z);
    z = mfma16(a1, b1, z);
    if (f * 16 + fr < MREAL) {
#pragma unroll
      for (int r = 0; r < 4; ++r) m = fmaxf(m, z[r]);
    }
  }
#pragma unroll
  for (int mk = 1; mk < 64; mk <<= 1) m = fmaxf(m, __shfl_xor(m, mk, 64));
  if (lane == 0) wred[w] = m;
  __syncthreads();
  if (t == 0) {
    float mm = fmaxf(fmaxf(wred[0], wred[1]), fmaxf(wred[2], wred[3]));
    u32 u = __float_as_uint(mm);
    u32 enc = (u & 0x80000000u) ? ~u : (u | 0x80000000u);
    atomicMax(maxslot, enc);
  }
}

// ------- fused ctx v3: kp features + kp^T @ [v | 1 | 0], 512 threads -------
__launch_bounds__(512)
__global__ void fused_ctx(const u16* __restrict__ kvbuf, const u16* __restrict__ projf,
                          const u32* __restrict__ maxslot, float* __restrict__ part) {
  __shared__ __align__(16) u16 kt[2][64 * 64]; // [n][dh] swizzled dbuf 16K
  __shared__ __align__(16) u16 kpL[MP * 64];   // [m][n] swizzled      36K
  __shared__ __align__(16) u16 vL[DHP * 64];   // [d][n] swizzled      12K
  int bid = blockIdx.x;
  int bh = bid >> 2, s = bid & 3;
  int b = bh >> 3, h = bh & 7;
  int t = threadIdx.x, lane = t & 63, w = t >> 6;
  int fr = lane & 15, fq = lane >> 4;
  int rg = w & 3, fh = w >> 2;           // feature-phase split
  int wq4 = w >> 1, wn = w & 1;          // gemm-phase split
  int i_base = (wq4 < 2) ? wq4 * 5 : 10 + (wq4 - 2) * 4;
  int i_cnt = (wq4 < 2) ? 5 : 4;

  if (t < 256) {  // vL rows 64..95: row 64 = ones, rest zero
    int rr = 64 + (t >> 3), sg = t & 7;
    u16 val = (rr == 64) ? (u16)0x3F80 : (u16)0;
    uint4 v4; u16* pv = (u16*)&v4;
#pragma unroll
    for (int e = 0; e < 8; ++e) pv[e] = val;
    *(uint4*)(vL + rr * 64 + sg * 8) = v4;
  }
  u32 enc = *maxslot;
  float gmax = __uint_as_float((enc & 0x80000000u) ? (enc & 0x7FFFFFFFu) : ~enc);
  const bf16x8* pf = (const bf16x8*)projf;

  bf16x8 pfr0[9], pfr1[9];
#pragma unroll
  for (int ff = 0; ff < 9; ++ff) {
    pfr0[ff] = pf[((fh * 9 + ff) * 2 + 0) * 64 + lane];
    pfr1[ff] = pf[((fh * 9 + ff) * 2 + 1) * 64 + lane];
  }

  f32x4 acc[5][3];
#pragma unroll
  for (int i = 0; i < 5; ++i)
#pragma unroll
    for (int j = 0; j < 3; ++j) acc[i][j] = f32x4{0.f, 0.f, 0.f, 0.f};

  int str = t >> 3;
  int sch = (t & 7) ^ (str & 7);
  int vr0 = t >> 4, vsg = t & 15;
  uint2 vra, vrb;

#define KT_LOAD(ci, n0)                                                        \
  gload_lds16(kvbuf + ((size_t)(b * NSEQ + (n0) + str)) * KVLD + h * 64 + sch * 8, \
              (char*)kt[ci] + t * 16)
#define V_LOAD(n0)                                                             \
  do {                                                                         \
    vra = *(const uint2*)(kvbuf + ((size_t)(b * NSEQ + (n0) + vr0)) * KVLD + 512 + h * 64 + vsg * 4); \
    vrb = *(const uint2*)(kvbuf + ((size_t)(b * NSEQ + (n0) + vr0 + 32)) * KVLD + 512 + h * 64 + vsg * 4); \
  } while (0)

  KT_LOAD(0, s * 1024);
  V_LOAD(s * 1024);
  int cur = 0;

  for (int tile = 0; tile < 16; ++tile) {
    int n0 = s * 1024 + tile * 64;
    WAITVM(0);

    {
      u16* pv = (u16*)&vra;
#pragma unroll
      for (int e = 0; e < 4; ++e) {
        int d = vsg * 4 + e, ch = (vr0 >> 3) ^ (d & 7);
        ((u16*)((char*)vL + d * 128 + ch * 16))[vr0 & 7] = pv[e];
      }
      u16* pw = (u16*)&vrb;
      int r2 = vr0 + 32;
#pragma unroll
      for (int e = 0; e < 4; ++e) {
        int d = vsg * 4 + e, ch = (r2 >> 3) ^ (d & 7);
        ((u16*)((char*)vL + d * 128 + ch * 16))[r2 & 7] = pw[e];
      }
    }
    if (tile < 15) { KT_LOAD(cur ^ 1, n0 + 64); V_LOAD(n0 + 64); }
    asm volatile("s_waitcnt lgkmcnt(0)" ::: "memory");
    __builtin_amdgcn_s_barrier();

    int rowa = rg * 16 + fr;
    bf16x8 a0 = *(const bf16x8*)((const char*)kt[cur] + rowa * 128 +
                                 ((fq ^ (fr & 7)) << 4));
    bf16x8 a1 = *(const bf16x8*)((const char*)kt[cur] + rowa * 128 +
                                 (((4 + fq) ^ (fr & 7)) << 4));

    float ss = 0.f;
#pragma unroll
    for (int e = 0; e < 8; ++e) {
      float x0 = bf2f((u16)a0[e]), x1 = bf2f((u16)a1[e]);
      ss += x0 * x0 + x1 * x1;
    }
    ss += __shfl_xor(ss, 16, 64);
    ss += __shfl_xor(ss, 32, 64);
    float dgv[4];
#pragma unroll
    for (int r4 = 0; r4 < 4; ++r4)
      dgv[r4] = __shfl(ss, fq * 4 + r4, 64) * HALF_DN2;

#pragma unroll
    for (int ff = 0; ff < 9; ++ff) {
      int f = fh * 9 + ff;
      f32x4 z = {0.f, 0.f, 0.f, 0.f};
      z = mfma16(a0, pfr0[ff], z);
      z = mfma16(a1, pfr1[ff], z);
      int col = f * 16 + fr;
      bool ok = col < MREAL;
      float k0v = ok ? (__expf(z[0] - dgv[0] - gmax) + KEPS) : 0.f;
      float k1v = ok ? (__expf(z[1] - dgv[1] - gmax) + KEPS) : 0.f;
      float k2v = ok ? (__expf(z[2] - dgv[2] - gmax) + KEPS) : 0.f;
      float k3v = ok ? (__expf(z[3] - dgv[3] - gmax) + KEPS) : 0.f;
      u32 lo, hi;
      asm("v_cvt_pk_bf16_f32 %0, %1, %2" : "=v"(lo) : "v"(k0v), "v"(k1v));
      asm("v_cvt_pk_bf16_f32 %0, %1, %2" : "=v"(hi) : "v"(k2v), "v"(k3v));
      uint2 pk2; pk2.x = lo; pk2.y = hi;
      int ch = (rg * 2 + (fq >> 1)) ^ (fr & 7);
      *(uint2*)((char*)kpL + col * 128 + ch * 16 + (fq & 1) * 8) = pk2;
    }
    asm volatile("s_waitcnt lgkmcnt(0)" ::: "memory");
    __builtin_amdgcn_s_barrier();

#pragma unroll
    for (int kc = 0; kc < 2; ++kc) {
      int rch = ((kc * 4 + fq) ^ (fr & 7)) << 4;
      bf16x8 av[5], bv[3];
#pragma unroll
      for (int i = 0; i < 5; ++i)
        if (i < i_cnt)
          av[i] = *(const bf16x8*)((const char*)kpL + ((i_base + i) * 16 + fr) * 128 + rch);
#pragma unroll
      for (int j = 0; j < 3; ++j)
        bv[j] = *(const bf16x8*)((const char*)vL + (wn * 48 + j * 16 + fr) * 128 + rch);
#pragma unroll
      for (int i = 0; i < 5; ++i)
        if (i < i_cnt)
#pragma unroll
          for (int j = 0; j < 3; ++j) acc[i][j] = mfma16(av[i], bv[j], acc[i][j]);
    }
    asm volatile("s_waitcnt lgkmcnt(0)" ::: "memory");
    __builtin_amdgcn_s_barrier();
    cur ^= 1;
  }
#undef KT_LOAD
#undef V_LOAD

  float* dst = part + ((size_t)bh * 4 + s) * MP * DHP;
#pragma unroll
  for (int i = 0; i < 5; ++i)
    if (i < i_cnt)
#pragma unroll
      for (int j = 0; j < 3; ++j) {
        int m = (i_base + i) * 16 + fq * 4;
        int c = wn * 48 + j * 16 + fr;
#pragma unroll
        for (int r = 0; r < 4; ++r) dst[(size_t)(m + r) * DHP + c] = acc[i][j][r];
      }
}

__launch_bounds__(256)
__global__ void ctx_reduce2(const float* __restrict__ part, u16* __restrict__ ctxT) {
  int bh = blockIdx.x, t = threadIdx.x;
  const float* p = part + (size_t)bh * 4 * MP * DHP;
  u16* dst = ctxT + (size_t)bh * DHP * MP;
  for (int idx = t; idx < DHP * MP; idx += 256) {
    int d = idx / MP, m = idx - d * MP;
    size_t o = (size_t)m * DHP + d;
    float v = p[o] + p[o + MP * DHP] + p[o + 2 * MP * DHP] + p[o + 3 * MP * DHP];
    dst[idx] = f2bf(v);   // ctxT[d][m] = ctx[m][d]
  }
}

// -- fused attn v4 (R5-verified): swapped feature MFMA + packed b64 qp writes,
//    qt XOR-swizzle, phase-2 bv distance-1 prefetch.
__launch_bounds__(256)
__global__ void fused_attn(const u16* __restrict__ qb, const u16* __restrict__ ctxT,
                           const u16* __restrict__ projf, u16* __restrict__ attnb) {
  __shared__ __align__(16) u16 qt[64 * 64];    // swizzled; reused as ob later
  __shared__ __align__(16) u16 qpL[64 * MPP];  // [n][m] padded stride
  __shared__ float dbuf[64];
  int bid = blockIdx.x;
  int bh = bid >> 6, nt = bid & 63;
  int b = bh >> 3, h = bh & 7;
  int n0 = nt * 64;
  int t = threadIdx.x, lane = t & 63, w = t >> 6;
  int wm = w >> 1, wn = w & 1;
  int fr = lane & 15, fq = lane >> 4;

#pragma unroll
  for (int it = 0; it < 4; ++it) {
    int idx = t + it * 256;
    int r = idx >> 4, sg = idx & 15;
    int dst = (r * 128 + sg * 8) ^ ((r & 7) << 4);
    *(uint2*)((char*)qt + dst) =
        *(const uint2*)(qb + ((size_t)(b * NSEQ + n0 + r)) * KVLD + h * 64 + sg * 4);
  }
  __syncthreads();

  int swz = (fr & 7) << 4;
  bf16x8 a0 = *(const bf16x8*)((const char*)qt +
                               (((w * 16 + fr) * 128 + fq * 16) ^ swz));
  bf16x8 a1 = *(const bf16x8*)((const char*)qt +
                               (((w * 16 + fr) * 128 + 64 + fq * 16) ^ swz));

  float ss = 0.f;
#pragma unroll
  for (int e = 0; e < 8; ++e) {
    float x0 = bf2f((u16)a0[e]), x1 = bf2f((u16)a1[e]);
    ss += x0 * x0 + x1 * x1;
  }
  ss += __shfl_xor(ss, 16, 64);
  ss += __shfl_xor(ss, 32, 64);
  float dg = ss * HALF_DN2;

  const bf16x8* pf = (const bf16x8*)projf;
  f32x4 accf[18];
#pragma unroll
  for (int f = 0; f < 18; ++f) {
    f32x4 z = {0.f, 0.f, 0.f, 0.f};
    z = mfma16(pf[(f * 2 + 0) * 64 + lane], a0, z);
    z = mfma16(pf[(f * 2 + 1) * 64 + lane], a1, z);
    accf[f] = z;
  }
  float mm = -1e30f;
#pragma unroll
  for (int f = 0; f < 18; ++f)
#pragma unroll
    for (int r = 0; r < 4; ++r) mm = fmaxf(mm, accf[f][r]);
  mm = fmaxf(mm, __shfl_xor(mm, 16, 64));
  mm = fmaxf(mm, __shfl_xor(mm, 32, 64));

  u16* qp = qpL + (w * 16 + fr) * MPP + fq * 4;
#pragma unroll
  for (int f = 0; f < 18; ++f) {
    float e0 = __expf(accf[f][0] - dg - mm) + KEPS;
    float e1 = __expf(accf[f][1] - dg - mm) + KEPS;
    float e2 = __expf(accf[f][2] - dg - mm) + KEPS;
    float e3 = __expf(accf[f][3] - dg - mm) + KEPS;
    u32 lo, hi;
    asm("v_cvt_pk_bf16_f32 %0, %1, %2" : "=v"(lo) : "v"(e0), "v"(e1));
    asm("v_cvt_pk_bf16_f32 %0, %1, %2" : "=v"(hi) : "v"(e2), "v"(e3));
    uint2 pk; pk.x = lo; pk.y = hi;
    *(uint2*)(qp + f * 16) = pk;
  }
  __syncthreads();

  const u16* cg = ctxT + (size_t)bh * DHP * MP;
  f32x4 acc2[2][3];
#pragma unroll
  for (int i = 0; i < 2; ++i)
#pragma unroll
    for (int j = 0; j < 3; ++j) acc2[i][j] = f32x4{0.f, 0.f, 0.f, 0.f};
  bf16x8 bvc[3];
#pragma unroll
  for (int j = 0; j < 3; ++j)
    bvc[j] = *(const bf16x8*)(cg + (size_t)(wn * 48 + j * 16 + fr) * MP + fq * 8);
#pragma unroll
  for (int kc = 0; kc < 9; ++kc) {
    bf16x8 bvn[3];
    if (kc < 8) {
#pragma unroll
      for (int j = 0; j < 3; ++j)
        bvn[j] = *(const bf16x8*)(cg + (size_t)(wn * 48 + j * 16 + fr) * MP +
                                  (kc + 1) * 32 + fq * 8);
    }
    bf16x8 av[2];
#pragma unroll
    for (int i = 0; i < 2; ++i)
      av[i] = *(const bf16x8*)(qpL + (wm * 32 + i * 16 + fr) * MPP + kc * 32 + fq * 8);
#pragma unroll
    for (int i = 0; i < 2; ++i)
#pragma unroll
      for (int j = 0; j < 3; ++j) acc2[i][j] = mfma16(av[i], bvc[j], acc2[i][j]);
    if (kc < 8) {
#pragma unroll
      for (int j = 0; j < 3; ++j) bvc[j] = bvn[j];
    }
  }
  if (wn == 1 && fr == 0) {
#pragma unroll
    for (int i = 0; i < 2; ++i) {
      int rl = wm * 32 + i * 16 + fq * 4;
#pragma unroll
      for (int r = 0; r < 4; ++r) dbuf[rl + r] = acc2[i][1][r];  // col 64 = denom
    }
  }
  __syncthreads();

  u16* ob = qt;  // reuse (qt reads all complete)
#pragma unroll
  for (int i = 0; i < 2; ++i)
#pragma unroll
    for (int j = 0; j < 3; ++j) {
      int cl = wn * 48 + j * 16 + fr;
      if (cl < 64) {
        int rl = wm * 32 + i * 16 + fq * 4;
#pragma unroll
        for (int r = 0; r < 4; ++r)
          ob[(rl + r) * 64 + cl] = f2bf(acc2[i][j][r] / dbuf[rl + r]);
      }
    }
  __syncthreads();

  u16* dst = attnb + ((size_t)(b * NSEQ + n0)) * KVLD + h * 64;
  for (int idx = t; idx < 64 * 8; idx += 256) {
    int r = idx >> 3, sg = idx & 7;
    *(uint4*)(dst + (size_t)r * KVLD + sg * 8) = *(const uint4*)(ob + r * 64 + sg * 8);
  }
}

// ---------------- workspace layout (total ~132.5 MB) ----------------
constexpr size_t OFF_WQT   = 0;                       // 512*512*2
constexpr size_t OFF_WKT   = 524288;                  // (wkt|wvt adjacent = kv weights)
constexpr size_t OFF_WVT   = 1048576;
constexpr size_t OFF_WOT   = 1572864;
constexpr size_t OFF_W1F   = 2097152;                 // 2MB: W1 frag layout
constexpr size_t OFF_W2F   = 4194304;                 // 2MB: W2 frag layout
constexpr size_t OFF_PROJF = 6328320;                 // 288*64*2 (fragment layout)
constexpr size_t OFF_MAX   = 6365184;                 // 256
constexpr size_t OFF_CTXT  = 6365440;                 // 64*96*288*2
constexpr size_t OFF_H     = 9904384;                 // 32 MB: LN1 out
constexpr size_t OFF_KV    = 43458816;                // 64 MB: [32768][1024] k|v -> q|attn
constexpr size_t OFF_PART  = 110567680;               // 64*4*288*96*4
constexpr size_t WS_NEED   = 138879232;

extern "C" void kernel_launch(void* const* d_in, const int* in_sizes, int n_in,
                              void* d_out, int out_size, void* d_ws, size_t ws_size,
                              hipStream_t stream) {
  const float* x    = (const float*)d_in[0];
  const float* w_q  = (const float*)d_in[1];
  const float* w_k  = (const float*)d_in[2];
  const float* w_v  = (const float*)d_in[3];
  const float* w_o  = (const float*)d_in[4];
  const float* b_o  = (const float*)d_in[5];
  const float* ln1g = (const float*)d_in[6];
  const float* ln1b = (const float*)d_in[7];
  const float* ln2g = (const float*)d_in[8];
  const float* ln2b = (const float*)d_in[9];
  const float* ffw1 = (const float*)d_in[10];
  const float* ffb1 = (const float*)d_in[11];
  const float* ffw2 = (const float*)d_in[12];
  const float* ffb2 = (const float*)d_in[13];
  const float* proj = (const float*)d_in[14];
  (void)in_sizes; (void)n_in; (void)out_size;

  float* dout = (float*)d_out;
  if (ws_size < WS_NEED) {  // diagnostic: absmax ~12345 => shrink workspace
    ws_sentinel<<<1, 1, 0, stream>>>(dout);
    return;
  }

  char* ws = (char*)d_ws;
  u16* wqt   = (u16*)(ws + OFF_WQT);
  u16* wkt   = (u16*)(ws + OFF_WKT);
  u16* wvt   = (u16*)(ws + OFF_WVT);
  u16* wot   = (u16*)(ws + OFF_WOT);
  u16* w1f   = (u16*)(ws + OFF_W1F);
  u16* w2f   = (u16*)(ws + OFF_W2F);
  u16* projf = (u16*)(ws + OFF_PROJF);
  u32* maxsl = (u32*)(ws + OFF_MAX);
  u16* ctxt  = (u16*)(ws + OFF_CTXT);
  u16* hbuf  = (u16*)(ws + OFF_H);    // LN1 out
  u16* kvbuf = (u16*)(ws + OFF_KV);   // [32768][1024]: k|v -> q|attn
  float* part = (float*)(ws + OFF_PART);

  hipMemsetAsync(maxsl, 0, 4, stream);

  transpose_cvt<<<256, 256, 0, stream>>>(w_q, wqt, 512, 512);
  transpose_cvt<<<256, 256, 0, stream>>>(w_k, wkt, 512, 512);
  transpose_cvt<<<256, 256, 0, stream>>>(w_v, wvt, 512, 512);
  transpose_cvt<<<256, 256, 0, stream>>>(w_o, wot, 512, 512);
  w1_prep<<<4096, 256, 0, stream>>>(ffw1, w1f);
  w2_prep<<<4096, 256, 0, stream>>>(ffw2, w2f);
  proj_prep<<<72, 256, 0, stream>>>(proj, projf);

  ln_fwd<<<8192, 256, 0, stream>>>(x, ln1g, ln1b, hbuf);
  // k|v in one GEMM (wkt/wvt stacked = 1024 output cols)
  gemm256<0><<<512, 512, 0, stream>>>(hbuf, 512, wkt, 512, 512, kvbuf, 1024, 1024, nullptr, nullptr);
  kmax_kernel<<<4096, 256, 0, stream>>>(kvbuf, projf, maxsl);
  fused_ctx<<<256, 512, 0, stream>>>(kvbuf, projf, maxsl, part);
  ctx_reduce2<<<64, 256, 0, stream>>>(part, ctxt);
  // q overwrites dead k-half (cols 0..511)
  gemm256<0><<<256, 512, 0, stream>>>(hbuf, 512, wqt, 512, 512, kvbuf, 512, 1024, nullptr, nullptr);
  // attn overwrites dead v-half (cols 512..1023)
  fused_attn<<<4096, 256, 0, stream>>>(kvbuf, ctxt, projf, kvbuf + 512);
  gemm256<1><<<256, 512, 0, stream>>>(kvbuf + 512, 1024, wot, 512, 512, dout, 512, 512, b_o, x);
  // fused FFN v6: LN2 + dout += gelu(LN2(dout) @ W1 + b1) @ W2 + b2
  ffn_fused<<<512, 512, 0, stream>>>(dout, ln2g, ln2b, w1f, w2f, ffb1, ffb2);
}